// Round 18
// baseline (4324.940 us; speedup 1.0000x reference)
//
#include <hip/hip_runtime.h>

#define T_STEPS 512
#define BATCH   128
#define DIN     256
#define DLAT    512

typedef __bf16 bf16x8 __attribute__((ext_vector_type(8)));
typedef float  f32x4  __attribute__((ext_vector_type(4)));
typedef int    i32x4  __attribute__((ext_vector_type(4)));
typedef unsigned long long u64;
typedef unsigned long long u64x2 __attribute__((ext_vector_type(2)));

__device__ __forceinline__ unsigned int f2bf2(float a, float b) {
  unsigned int ua = __float_as_uint(a);
  unsigned int ub = __float_as_uint(b);
  ua = (ua + 0x7FFFu + ((ua >> 16) & 1u)) >> 16;
  ub = (ub + 0x7FFFu + ((ub >> 16) & 1u)) >> 16;
  return ua | (ub << 16);
}

__device__ __forceinline__ uint4 pack8(float4 f0, float4 f1) {
  uint4 r;
  r.x = f2bf2(f0.x, f0.y);
  r.y = f2bf2(f0.z, f0.w);
  r.z = f2bf2(f1.x, f1.y);
  r.w = f2bf2(f1.z, f1.w);
  return r;
}

// ---------------- Kernel P: prepack Wh fp32 -> bf16 row-major in workspace ----------------
extern "C" __global__ __launch_bounds__(256) void pk_wh(
    const float* __restrict__ Wh, unsigned int* __restrict__ out) {
  int idx = blockIdx.x * 256 + threadIdx.x;   // 0..32767, 8 f32 each
  const float* src = Wh + (long)idx * 8;
  float4 f0 = *(const float4*)src;
  float4 f1 = *(const float4*)(src + 4);
  uint4 v = pack8(f0, f1);
  *(uint4*)(out + (long)idx * 4) = v;
}

// ---------------- Kernel H: pre-pack h0 (bf16) into exchange slot 0 ----------------
// Layout must match rnn_scan reads: slot0 + group g (<<11 u64) + row m (<<7) + chunk j,
// chunk j = 4 consecutive n (low 16 bits = lowest n).
extern "C" __global__ __launch_bounds__(256) void pk_h0(
    const float* __restrict__ h0, u64* __restrict__ hx) {
  int idx = blockIdx.x * 256 + threadIdx.x;   // 0..16383
  int r = idx >> 7, j = idx & 127;            // batch row, u64 chunk
  int g = r >> 4, m = r & 15;
  float4 f = *(const float4*)(h0 + (long)r * DLAT + j * 4);
  u64 v = ((u64)f2bf2(f.z, f.w) << 32) | (u64)f2bf2(f.x, f.y);
  hx[((long)g << 11) + (m << 7) + j] = v;
}

// ---------------- Kernel A: Xi = X @ Wi^T + (bi + bh), written into d_out ----------------
extern "C" __global__ __launch_bounds__(256) void xi_gemm(
    const float* __restrict__ X, const float* __restrict__ Wi,
    const float* __restrict__ bi, const float* __restrict__ bh,
    float* __restrict__ XiOut) {
  extern __shared__ char smem[];
  char*  sX    = smem;                      // 65536 B: [128 rows][512 B] swizzled
  char*  sW    = smem + 65536;              // 65536 B
  float* sBias = (float*)(smem + 131072);   // 128 floats

  const int tid = threadIdx.x;
  const long m0 = (long)blockIdx.x * 128;   // over T*B = 65536
  const int  n0 = blockIdx.y * 128;         // over DLAT

  #pragma unroll
  for (int c = 0; c < 16; ++c) {
    int id = c * 256 + tid;                 // 0..4095
    int r  = id >> 5;                       // 0..127
    int kc = (id & 31) << 3;                // 0..248
    const float* sx = X + (m0 + r) * DIN + kc;
    float4 a0 = *(const float4*)sx;
    float4 a1 = *(const float4*)(sx + 4);
    int ax = ((r << 9) + (kc << 1)) ^ ((r & 7) << 4);
    *(uint4*)(sX + ax) = pack8(a0, a1);
    const float* sw = Wi + (n0 + r) * DIN + kc;
    float4 b0 = *(const float4*)sw;
    float4 b1 = *(const float4*)(sw + 4);
    *(uint4*)(sW + ax) = pack8(b0, b1);
  }
  if (tid < 128) sBias[tid] = bi[n0 + tid] + bh[n0 + tid];
  __syncthreads();

  const int w = tid >> 6, lane = tid & 63;
  const int wm = (w >> 1) * 64, wn = (w & 1) * 64;
  const int lm = lane & 15, lq = lane >> 4;

  f32x4 acc[4][4];
  #pragma unroll
  for (int nt = 0; nt < 4; ++nt) {
    float bv = sBias[wn + nt * 16 + lm];
    #pragma unroll
    for (int mt = 0; mt < 4; ++mt) acc[mt][nt] = f32x4{bv, bv, bv, bv};
  }

  #pragma unroll
  for (int k0 = 0; k0 < 8; ++k0) {
    int kb = (k0 << 6) + (lq << 4);
    bf16x8 af[4], bfr[4];
    #pragma unroll
    for (int mt = 0; mt < 4; ++mt) {
      int row = wm + mt * 16 + lm;
      int ax = ((row << 9) + kb) ^ ((row & 7) << 4);
      af[mt] = __builtin_bit_cast(bf16x8, *(uint4*)(sX + ax));
    }
    #pragma unroll
    for (int nt = 0; nt < 4; ++nt) {
      int row = wn + nt * 16 + lm;
      int ax = ((row << 9) + kb) ^ ((row & 7) << 4);
      bfr[nt] = __builtin_bit_cast(bf16x8, *(uint4*)(sW + ax));
    }
    #pragma unroll
    for (int mt = 0; mt < 4; ++mt)
      #pragma unroll
      for (int nt = 0; nt < 4; ++nt)
        acc[mt][nt] = __builtin_amdgcn_mfma_f32_16x16x32_bf16(af[mt], bfr[nt], acc[mt][nt], 0, 0, 0);
  }

  #pragma unroll
  for (int mt = 0; mt < 4; ++mt) {
    #pragma unroll
    for (int e = 0; e < 4; ++e) {
      long m = m0 + wm + mt * 16 + (lq << 2) + e;
      float* dst = XiOut + m * DLAT + n0 + wn + lm;
      #pragma unroll
      for (int nt = 0; nt < 4; ++nt)
        dst[nt * 16] = acc[mt][nt][e];
    }
  }
}

// ---------------- Kernel B: n-split x4 recurrence, register-direct L3 exchange ----------
// 32 blocks = 8 batch-groups x 4 n-quarters; 512 threads; wave w owns ONE n-tile
// (nt = q*128 + w*16), Wh slice = wreg[16] = 64 regs (AGPR-resident via AV operand
// class). NO LDS AT ALL in the hot loop (r17's rebuild path -- L3->VGPR->LDS->barrier->
// VGPR -- was ~0.5 us/step of pure staging): each lane atomically loads its 16 MFMA
// B-fragments (2 u64 each) STRAIGHT from the L3 exchange buffer into registers, own
// and sibling quarters symmetrically. One barrier + one flag-poll per step.
// Sync skeleton (proven r13-r17): publish h (1 u64/thread, relaxed agent atomic =
// write-through L3) -> vmcnt(0) drain -> barrier -> tid0 STOREs single-writer flag ->
// HO store + xi prefetch in poll shadow -> lanes 0-2 poll 3 sibling flags (__any).
// Parity depth-2 safety: owner's t+2 overwrite of slot (t&1... same parity) is gated by
// poll(flag[t+1]); sibling stored flag[t+1] after its t+1 barrier, after its t+1 MFMA,
// whose B-loads of the slot completed. h0 pre-packed into slot 0 by pk_h0 (no step-0
// special case). flags zeroed per launch by hipMemsetAsync (graph-safe).
extern "C" __global__ __launch_bounds__(512, 2) void rnn_scan(
    const unsigned short* __restrict__ WhP, float* __restrict__ HO,
    u64* __restrict__ hx, unsigned int* __restrict__ flags) {
  const int tid = threadIdx.x;
  const int w = tid >> 6, lane = tid & 63;
  const int lm = lane & 15, lq = lane >> 4;
  const int g  = blockIdx.x & 7;      // batch group: rows [g*16, g*16+16)
  const int q  = blockIdx.x >> 3;     // n-quarter:  cols [q*128, q*128+128)
  const int r0 = g << 4;
  const int nt = (q << 7) + (w << 4); // wave's n-tile

  // Wh slice: lane holds Wh[nt+lm][kq*32 + lq*8 .. +7], kq = 0..15 (64 regs)
  i32x4 wreg[16];
  {
    const unsigned short* base = WhP + (nt + lm) * DLAT + (lq << 3);
    #pragma unroll
    for (int kq = 0; kq < 16; ++kq)
      wreg[kq] = *(const i32x4*)(base + kq * 32);
    #pragma unroll
    for (int kq = 0; kq < 16; ++kq)
      asm("" : "+v"(wreg[kq]));   // anti-remat pin (asm def)
  }

  const int ncol = nt + (lq << 2);               // thread's 4 consecutive n (row m = lm)
  unsigned int* fgrp = flags + (g << 11);        // flags[g][q][t]: (q<<9)+t
  const int sq = (q + 1 + lane) & 3;             // lanes 0..2 -> the 3 siblings
  u64* hgrp = hx + ((long)g << 11);              // group base (slot offset added per step)
  const int fb  = (lm << 7) + (lq << 1);         // B-frag base: row lm, + kq*8 u64
  const int pub = (lm << 7) + (ncol >> 2);       // publish slot for own 4 n-values

  // prefetch xi for t = 0 (Xi lives in HO, written by xi_gemm)
  float4 xi = *(const float4*)(HO + (long)(r0 + lm) * DLAT + ncol);

  for (int t = 0; t < T_STEPS; ++t) {
    const u64* hs = hgrp + ((long)(t & 1) << 14);   // read slot for h_t

    // load all 16 B-fragments (2 u64 each) straight from L3 into registers
    u64 fA[16], fB[16];
    #pragma unroll
    for (int kq = 0; kq < 16; ++kq) {
      fA[kq] = __hip_atomic_load(&hs[fb + kq * 8],     __ATOMIC_RELAXED, __HIP_MEMORY_SCOPE_AGENT);
      fB[kq] = __hip_atomic_load(&hs[fb + kq * 8 + 1], __ATOMIC_RELAXED, __HIP_MEMORY_SCOPE_AGENT);
    }

    // z^T[n][m] = sum_k Wh[n][k] * h[m][k]; 4 chains for MFMA-latency ILP
    f32x4 a0 = f32x4{0.f, 0.f, 0.f, 0.f};
    f32x4 a1 = f32x4{0.f, 0.f, 0.f, 0.f};
    f32x4 a2 = f32x4{0.f, 0.f, 0.f, 0.f};
    f32x4 a3 = f32x4{0.f, 0.f, 0.f, 0.f};
    #pragma unroll
    for (int kq = 0; kq < 16; kq += 4) {
      u64x2 p0 = u64x2{fA[kq],     fB[kq]};
      u64x2 p1 = u64x2{fA[kq + 1], fB[kq + 1]};
      u64x2 p2 = u64x2{fA[kq + 2], fB[kq + 2]};
      u64x2 p3 = u64x2{fA[kq + 3], fB[kq + 3]};
      a0 = __builtin_amdgcn_mfma_f32_16x16x32_bf16(
          __builtin_bit_cast(bf16x8, wreg[kq]),     __builtin_bit_cast(bf16x8, p0), a0, 0, 0, 0);
      a1 = __builtin_amdgcn_mfma_f32_16x16x32_bf16(
          __builtin_bit_cast(bf16x8, wreg[kq + 1]), __builtin_bit_cast(bf16x8, p1), a1, 0, 0, 0);
      a2 = __builtin_amdgcn_mfma_f32_16x16x32_bf16(
          __builtin_bit_cast(bf16x8, wreg[kq + 2]), __builtin_bit_cast(bf16x8, p2), a2, 0, 0, 0);
      a3 = __builtin_amdgcn_mfma_f32_16x16x32_bf16(
          __builtin_bit_cast(bf16x8, wreg[kq + 3]), __builtin_bit_cast(bf16x8, p3), a3, 0, 0, 0);
    }

    // h = tanh(z + xi)
    float hv[4];
    #pragma unroll
    for (int e = 0; e < 4; ++e) {
      float z = (a0[e] + a1[e]) + (a2[e] + a3[e]) + ((float*)&xi)[e];
      float ex = __expf(2.0f * z);
      hv[e] = 1.0f - 2.0f / (ex + 1.0f);
    }

    if (t + 1 < T_STEPS) {
      // publish h_{t+1} (8-B L3 write); drain only this, then the single barrier
      u64 v = ((u64)f2bf2(hv[2], hv[3]) << 32) | (u64)f2bf2(hv[0], hv[1]);
      __hip_atomic_store(&hgrp[((long)((t + 1) & 1) << 14) + pub], v,
                         __ATOMIC_RELAXED, __HIP_MEMORY_SCOPE_AGENT);
      asm volatile("s_waitcnt vmcnt(0)" ::: "memory");
      __syncthreads();   // all 512 publishes at L3

      // single-writer flag: tid0 STOREs 1 (no RMW)
      if (tid == 0)
        __hip_atomic_store(&fgrp[(q << 9) + t], 1u,
                           __ATOMIC_RELAXED, __HIP_MEMORY_SCOPE_AGENT);

      // poll shadow: HO store + next-xi prefetch (acks fold into next step's drain)
      {
        float4 o; o.x = hv[0]; o.y = hv[1]; o.z = hv[2]; o.w = hv[3];
        *(float4*)(HO + ((long)t * BATCH + r0 + lm) * DLAT + ncol) = o;
        xi = *(const float4*)(HO + ((long)(t + 1) * BATCH + r0 + lm) * DLAT + ncol);
      }

      // per-wave read-only poll: lanes 0-2 watch the 3 sibling flags
      for (;;) {
        unsigned int fv = (lane < 3)
            ? __hip_atomic_load(&fgrp[(sq << 9) + t], __ATOMIC_RELAXED, __HIP_MEMORY_SCOPE_AGENT)
            : 1u;
        if (!__any(fv == 0u)) break;
        __builtin_amdgcn_s_sleep(1);
      }
      asm volatile("" ::: "memory");
    } else {
      float4 o; o.x = hv[0]; o.y = hv[1]; o.z = hv[2]; o.w = hv[3];
      *(float4*)(HO + ((long)t * BATCH + r0 + lm) * DLAT + ncol) = o;
    }
  }
}

extern "C" void kernel_launch(void* const* d_in, const int* in_sizes, int n_in,
                              void* d_out, int out_size, void* d_ws, size_t ws_size,
                              hipStream_t stream) {
  const float* X  = (const float*)d_in[0];
  const float* h0 = (const float*)d_in[1];
  const float* Wi = (const float*)d_in[2];
  const float* bi = (const float*)d_in[3];
  const float* Wh = (const float*)d_in[4];
  const float* bh = (const float*)d_in[5];
  float* out = (float*)d_out;

  // ws: [0,512K) WhP bf16; [512K,768K) hx (2 parity slots x 8 groups x 16 KB);
  //     [768K,832K) flags u32[8][4][512] = 64 KB (single-writer, zeroed per launch)
  unsigned int* whp   = (unsigned int*)d_ws;
  u64*          hx    = (u64*)((char*)d_ws + 524288);
  unsigned int* flags = (unsigned int*)((char*)d_ws + 786432);

  hipMemsetAsync(flags, 0, 65536, stream);   // re-zeroed on every (graph) replay

  hipFuncSetAttribute((const void*)xi_gemm, hipFuncAttributeMaxDynamicSharedMemorySize, 131584);

  pk_wh<<<128, 256, 0, stream>>>(Wh, whp);
  pk_h0<<<64, 256, 0, stream>>>(h0, hx);
  xi_gemm<<<dim3(512, 4), 256, 131584, stream>>>(X, Wi, bi, bh, out);
  rnn_scan<<<32, 512, 0, stream>>>((const unsigned short*)whp, out, hx, flags);
}

// Round 19
// 1162.586 us; speedup vs baseline: 3.7201x; 3.7201x over previous
//
#include <hip/hip_runtime.h>

#define T_STEPS 512
#define BATCH   128
#define DIN     256
#define DLAT    512

typedef __bf16 bf16x8 __attribute__((ext_vector_type(8)));
typedef float  f32x4  __attribute__((ext_vector_type(4)));
typedef int    i32x4  __attribute__((ext_vector_type(4)));
typedef unsigned long long u64;

__device__ __forceinline__ unsigned int f2bf2(float a, float b) {
  unsigned int ua = __float_as_uint(a);
  unsigned int ub = __float_as_uint(b);
  ua = (ua + 0x7FFFu + ((ua >> 16) & 1u)) >> 16;
  ub = (ub + 0x7FFFu + ((ub >> 16) & 1u)) >> 16;
  return ua | (ub << 16);
}

__device__ __forceinline__ uint4 pack8(float4 f0, float4 f1) {
  uint4 r;
  r.x = f2bf2(f0.x, f0.y);
  r.y = f2bf2(f0.z, f0.w);
  r.z = f2bf2(f1.x, f1.y);
  r.w = f2bf2(f1.z, f1.w);
  return r;
}

// ---------------- Kernel P: prepack Wh fp32 -> bf16 row-major in workspace ----------------
extern "C" __global__ __launch_bounds__(256) void pk_wh(
    const float* __restrict__ Wh, unsigned int* __restrict__ out) {
  int idx = blockIdx.x * 256 + threadIdx.x;   // 0..32767, 8 f32 each
  const float* src = Wh + (long)idx * 8;
  float4 f0 = *(const float4*)src;
  float4 f1 = *(const float4*)(src + 4);
  uint4 v = pack8(f0, f1);
  *(uint4*)(out + (long)idx * 4) = v;
}

// ---------------- Kernel A: Xi = X @ Wi^T + (bi + bh), written into d_out ----------------
extern "C" __global__ __launch_bounds__(256) void xi_gemm(
    const float* __restrict__ X, const float* __restrict__ Wi,
    const float* __restrict__ bi, const float* __restrict__ bh,
    float* __restrict__ XiOut) {
  extern __shared__ char smem[];
  char*  sX    = smem;                      // 65536 B: [128 rows][512 B] swizzled
  char*  sW    = smem + 65536;              // 65536 B
  float* sBias = (float*)(smem + 131072);   // 128 floats

  const int tid = threadIdx.x;
  const long m0 = (long)blockIdx.x * 128;   // over T*B = 65536
  const int  n0 = blockIdx.y * 128;         // over DLAT

  #pragma unroll
  for (int c = 0; c < 16; ++c) {
    int id = c * 256 + tid;                 // 0..4095
    int r  = id >> 5;                       // 0..127
    int kc = (id & 31) << 3;                // 0..248
    const float* sx = X + (m0 + r) * DIN + kc;
    float4 a0 = *(const float4*)sx;
    float4 a1 = *(const float4*)(sx + 4);
    int ax = ((r << 9) + (kc << 1)) ^ ((r & 7) << 4);
    *(uint4*)(sX + ax) = pack8(a0, a1);
    const float* sw = Wi + (n0 + r) * DIN + kc;
    float4 b0 = *(const float4*)sw;
    float4 b1 = *(const float4*)(sw + 4);
    *(uint4*)(sW + ax) = pack8(b0, b1);
  }
  if (tid < 128) sBias[tid] = bi[n0 + tid] + bh[n0 + tid];
  __syncthreads();

  const int w = tid >> 6, lane = tid & 63;
  const int wm = (w >> 1) * 64, wn = (w & 1) * 64;
  const int lm = lane & 15, lq = lane >> 4;

  f32x4 acc[4][4];
  #pragma unroll
  for (int nt = 0; nt < 4; ++nt) {
    float bv = sBias[wn + nt * 16 + lm];
    #pragma unroll
    for (int mt = 0; mt < 4; ++mt) acc[mt][nt] = f32x4{bv, bv, bv, bv};
  }

  #pragma unroll
  for (int k0 = 0; k0 < 8; ++k0) {
    int kb = (k0 << 6) + (lq << 4);
    bf16x8 af[4], bfr[4];
    #pragma unroll
    for (int mt = 0; mt < 4; ++mt) {
      int row = wm + mt * 16 + lm;
      int ax = ((row << 9) + kb) ^ ((row & 7) << 4);
      af[mt] = __builtin_bit_cast(bf16x8, *(uint4*)(sX + ax));
    }
    #pragma unroll
    for (int nt = 0; nt < 4; ++nt) {
      int row = wn + nt * 16 + lm;
      int ax = ((row << 9) + kb) ^ ((row & 7) << 4);
      bfr[nt] = __builtin_bit_cast(bf16x8, *(uint4*)(sW + ax));
    }
    #pragma unroll
    for (int mt = 0; mt < 4; ++mt)
      #pragma unroll
      for (int nt = 0; nt < 4; ++nt)
        acc[mt][nt] = __builtin_amdgcn_mfma_f32_16x16x32_bf16(af[mt], bfr[nt], acc[mt][nt], 0, 0, 0);
  }

  #pragma unroll
  for (int mt = 0; mt < 4; ++mt) {
    #pragma unroll
    for (int e = 0; e < 4; ++e) {
      long m = m0 + wm + mt * 16 + (lq << 2) + e;
      float* dst = XiOut + m * DLAT + n0 + wn + lm;
      #pragma unroll
      for (int nt = 0; nt < 4; ++nt)
        dst[nt * 16] = acc[mt][nt][e];
    }
  }
}

// ---------------- Kernel B: n-split x4 recurrence, L3-coherent exchange ----------------
// 32 blocks = 8 batch-groups x 4 n-quarters; 512 threads; wave w owns ONE n-tile
// (nt = q*128 + w*16), Wh slice = wreg[16] = 64 regs (AGPR-resident via AV operand
// class). LDS = 16 KB sH only (r18 lesson: every wave consumes ALL of h, so LDS
// broadcast dedup is essential -- register-direct L3 B-loads were 8x redundant, 3.5x
// slower). Sync skeleton proven r13-r17: publish-first vmcnt drain, barrier, tid0
// single-writer flag STORE, own-slice local, HO/xi in shadow.
// ROUND-19 change: FUSED speculative poll+rebuild -- each poll iteration loads the
// thread's 3 sibling data u64s TOGETHER with the 3 flags (lanes 0-2); when the ballot
// sees all flags, the same-iteration data is committed. Safety: writer stores flag only
// after its data's vmcnt(0) ack (data at L3 at T1, flag at T2 >= T1+~300cy); reader's
// same-iteration data/flag samples skew by tens of cycles << 300cy, so flag==1 implies
// the data sample is post-T1 (fully written). Partial values only in DISCARDED
// iterations. Collapses flag-detect + rebuild from 2 L3 RTTs to 1; s_sleep removed
// (iteration paced by its own load RTT).
// Depth-2 parity safety unchanged: committed reads precede my flag[t+1] (barrier
// order), which gates the owner's parity-slot overwrite at t+2.
extern "C" __global__ __launch_bounds__(512, 2) void rnn_scan(
    const float* __restrict__ h0, const unsigned short* __restrict__ WhP,
    float* __restrict__ HO, u64* __restrict__ hx,
    unsigned int* __restrict__ flags) {
  __shared__ uint4 sH4[1024];   // 16 KB: [m=16][k=512] bf16, rows 1024 B, XOR-swizzled
  char* sH = (char*)sH4;

  const int tid = threadIdx.x;
  const int w = tid >> 6, lane = tid & 63;
  const int lm = lane & 15, lq = lane >> 4;
  const int g  = blockIdx.x & 7;      // batch group: rows [g*16, g*16+16)
  const int q  = blockIdx.x >> 3;     // n-quarter:  cols [q*128, q*128+128)
  const int r0 = g << 4;
  const int nt = (q << 7) + (w << 4); // wave's n-tile

  // Wh slice: lane holds Wh[nt+lm][kq*32 + lq*8 .. +7], kq = 0..15 (64 regs)
  i32x4 wreg[16];
  {
    const unsigned short* base = WhP + (nt + lm) * DLAT + (lq << 3);
    #pragma unroll
    for (int kq = 0; kq < 16; ++kq)
      wreg[kq] = *(const i32x4*)(base + kq * 32);
    #pragma unroll
    for (int kq = 0; kq < 16; ++kq)
      asm("" : "+v"(wreg[kq]));   // anti-remat pin (asm def)
  }

  // initial h from h0: 16 rows x 64 chunks(16B) = 1024 -> 2 iters x 512 threads
  #pragma unroll
  for (int c = 0; c < 2; ++c) {
    int id = c * 512 + tid;
    int m = id >> 6, kc = (id & 63) << 3;
    const float* src = h0 + (r0 + m) * DLAT + kc;
    float4 f0 = *(const float4*)src;
    float4 f1 = *(const float4*)(src + 4);
    int ax = ((m << 10) + (kc << 1)) ^ ((m & 7) << 4);
    *(uint4*)(sH + ax) = pack8(f0, f1);
  }
  __syncthreads();

  const int mask  = (lm & 7) << 4;
  const int hbase = (lm << 10) + (lq << 4);
  const int ncol  = nt + (lq << 2);              // thread's 4 consecutive n (row m = lm)
  unsigned int* fgrp = flags + (g << 11);        // flags[g][q][t]: (q<<9)+t
  const int sq = (q + 1 + lane) & 3;             // lanes 0..2 -> the 3 siblings
  const int rm = tid >> 5, rj = tid & 31;        // rebuild: row 0..15, chunk 0..31
  const int q1 = (q + 1) & 3, q2 = (q + 2) & 3, q3 = (q + 3) & 3;

  // prefetch xi for t = 0 (Xi lives in HO, written by xi_gemm)
  float4 xi = *(const float4*)(HO + (long)(r0 + lm) * DLAT + ncol);

  for (int t = 0; t < T_STEPS; ++t) {
    // z^T[n][m] = sum_k Wh[n][k] * h[m][k]; 4 chains (depth 4) for MFMA-latency ILP
    f32x4 a0 = f32x4{0.f, 0.f, 0.f, 0.f};
    f32x4 a1 = f32x4{0.f, 0.f, 0.f, 0.f};
    f32x4 a2 = f32x4{0.f, 0.f, 0.f, 0.f};
    f32x4 a3 = f32x4{0.f, 0.f, 0.f, 0.f};
    #pragma unroll
    for (int kq = 0; kq < 16; kq += 4) {
      bf16x8 hb0 = __builtin_bit_cast(bf16x8, *(uint4*)(sH + ((hbase + kq * 64) ^ mask)));
      bf16x8 hb1 = __builtin_bit_cast(bf16x8, *(uint4*)(sH + ((hbase + (kq + 1) * 64) ^ mask)));
      bf16x8 hb2 = __builtin_bit_cast(bf16x8, *(uint4*)(sH + ((hbase + (kq + 2) * 64) ^ mask)));
      bf16x8 hb3 = __builtin_bit_cast(bf16x8, *(uint4*)(sH + ((hbase + (kq + 3) * 64) ^ mask)));
      a0 = __builtin_amdgcn_mfma_f32_16x16x32_bf16(
          __builtin_bit_cast(bf16x8, wreg[kq]), hb0, a0, 0, 0, 0);
      a1 = __builtin_amdgcn_mfma_f32_16x16x32_bf16(
          __builtin_bit_cast(bf16x8, wreg[kq + 1]), hb1, a1, 0, 0, 0);
      a2 = __builtin_amdgcn_mfma_f32_16x16x32_bf16(
          __builtin_bit_cast(bf16x8, wreg[kq + 2]), hb2, a2, 0, 0, 0);
      a3 = __builtin_amdgcn_mfma_f32_16x16x32_bf16(
          __builtin_bit_cast(bf16x8, wreg[kq + 3]), hb3, a3, 0, 0, 0);
    }

    // h = tanh(z + xi)
    float hv[4];
    #pragma unroll
    for (int e = 0; e < 4; ++e) {
      float z = (a0[e] + a1[e]) + (a2[e] + a3[e]) + ((float*)&xi)[e];
      float ex = __expf(2.0f * z);
      hv[e] = 1.0f - 2.0f / (ex + 1.0f);
    }

    if (t + 1 < T_STEPS) {
      u64* hxg = hx + ((long)(t & 1) << 14) + ((long)g << 11);  // parity 16384, group 2048 u64
      u64 v = ((u64)f2bf2(hv[2], hv[3]) << 32) | (u64)f2bf2(hv[0], hv[1]);

      // publish for siblings (8-B L3 write); drain waits only on this
      __hip_atomic_store(&hxg[(lm << 7) + (ncol >> 2)], v,
                         __ATOMIC_RELAXED, __HIP_MEMORY_SCOPE_AGENT);
      asm volatile("s_waitcnt vmcnt(0)" ::: "memory");
      __syncthreads();   // all MFMA reads done + ALL publishes at L3

      // single-writer flag: tid0 STOREs 1 (no RMW)
      if (tid == 0)
        __hip_atomic_store(&fgrp[(q << 9) + t], 1u,
                           __ATOMIC_RELAXED, __HIP_MEMORY_SCOPE_AGENT);

      // overlap window: own-slice into sH, HO store, next-xi prefetch
      {
        int ax = ((lm << 10) + (ncol << 1)) ^ mask;
        *(u64*)(sH + ax) = v;   // same bit pattern (2x u32 of 2x bf16)
        float4 o; o.x = hv[0]; o.y = hv[1]; o.z = hv[2]; o.w = hv[3];
        *(float4*)(HO + ((long)t * BATCH + r0 + lm) * DLAT + ncol) = o;
        xi = *(const float4*)(HO + ((long)(t + 1) * BATCH + r0 + lm) * DLAT + ncol);
      }

      // FUSED speculative poll + rebuild: data sampled in the same iteration where
      // all 3 sibling flags read 1 is provably post-publish (see header comment).
      u64 d1, d2, d3;
      for (;;) {
        d1 = __hip_atomic_load(&hxg[(rm << 7) + (q1 << 5) + rj],
                               __ATOMIC_RELAXED, __HIP_MEMORY_SCOPE_AGENT);
        d2 = __hip_atomic_load(&hxg[(rm << 7) + (q2 << 5) + rj],
                               __ATOMIC_RELAXED, __HIP_MEMORY_SCOPE_AGENT);
        d3 = __hip_atomic_load(&hxg[(rm << 7) + (q3 << 5) + rj],
                               __ATOMIC_RELAXED, __HIP_MEMORY_SCOPE_AGENT);
        unsigned int fv = (lane < 3)
            ? __hip_atomic_load(&fgrp[(sq << 9) + t], __ATOMIC_RELAXED, __HIP_MEMORY_SCOPE_AGENT)
            : 1u;
        if (!__any(fv == 0u)) break;
      }
      asm volatile("" ::: "memory");

      // commit the 3 sibling quarters to sH
      {
        int ax1 = ((rm << 10) + (((q1 << 5) + rj) << 3)) ^ ((rm & 7) << 4);
        int ax2 = ((rm << 10) + (((q2 << 5) + rj) << 3)) ^ ((rm & 7) << 4);
        int ax3 = ((rm << 10) + (((q3 << 5) + rj) << 3)) ^ ((rm & 7) << 4);
        *(u64*)(sH + ax1) = d1;
        *(u64*)(sH + ax2) = d2;
        *(u64*)(sH + ax3) = d3;
      }

      __syncthreads();   // barrier #2: sH fully rebuilt before next step's MFMA reads
    } else {
      float4 o; o.x = hv[0]; o.y = hv[1]; o.z = hv[2]; o.w = hv[3];
      *(float4*)(HO + ((long)t * BATCH + r0 + lm) * DLAT + ncol) = o;
    }
  }
}

extern "C" void kernel_launch(void* const* d_in, const int* in_sizes, int n_in,
                              void* d_out, int out_size, void* d_ws, size_t ws_size,
                              hipStream_t stream) {
  const float* X  = (const float*)d_in[0];
  const float* h0 = (const float*)d_in[1];
  const float* Wi = (const float*)d_in[2];
  const float* bi = (const float*)d_in[3];
  const float* Wh = (const float*)d_in[4];
  const float* bh = (const float*)d_in[5];
  float* out = (float*)d_out;

  // ws: [0,512K) WhP bf16; [512K,768K) hx (2 parities x 8 groups x 16 KB);
  //     [768K,832K) flags u32[8][4][512] = 64 KB (single-writer, zeroed per launch)
  unsigned int* whp   = (unsigned int*)d_ws;
  u64*          hx    = (u64*)((char*)d_ws + 524288);
  unsigned int* flags = (unsigned int*)((char*)d_ws + 786432);

  hipMemsetAsync(flags, 0, 65536, stream);   // re-zeroed on every (graph) replay

  hipFuncSetAttribute((const void*)xi_gemm, hipFuncAttributeMaxDynamicSharedMemorySize, 131584);

  pk_wh<<<128, 256, 0, stream>>>(Wh, whp);
  xi_gemm<<<dim3(512, 4), 256, 131584, stream>>>(X, Wi, bi, bh, out);
  rnn_scan<<<32, 512, 0, stream>>>(h0, (const unsigned short*)whp, out, hx, flags);
}